// Round 1
// baseline (799.122 us; speedup 1.0000x reference)
//
#include <hip/hip_runtime.h>
#include <stdint.h>
#include <float.h>

#define NUM_SAMPLES 50
#define EPSF 1e-8f
#define PENALTY 1e-4f
#define REV_SCALE 0.1f

// ---------------- JAX threefry2x32 (exact) ----------------
__device__ __forceinline__ uint32_t rotl32(uint32_t v, int d) {
  return (v << d) | (v >> (32 - d));
}

__device__ __forceinline__ void threefry2x32(uint32_t k0, uint32_t k1,
                                             uint32_t x0, uint32_t x1,
                                             uint32_t& o0, uint32_t& o1) {
  const uint32_t k2 = k0 ^ k1 ^ 0x1BD11BDAu;
  x0 += k0; x1 += k1;
#define TF_ROUND(r) { x0 += x1; x1 = rotl32(x1, (r)); x1 ^= x0; }
  TF_ROUND(13) TF_ROUND(15) TF_ROUND(26) TF_ROUND(6)
  x0 += k1; x1 += k2 + 1u;
  TF_ROUND(17) TF_ROUND(29) TF_ROUND(16) TF_ROUND(24)
  x0 += k2; x1 += k0 + 2u;
  TF_ROUND(13) TF_ROUND(15) TF_ROUND(26) TF_ROUND(6)
  x0 += k0; x1 += k1 + 3u;
  TF_ROUND(17) TF_ROUND(29) TF_ROUND(16) TF_ROUND(24)
  x0 += k1; x1 += k2 + 4u;
  TF_ROUND(13) TF_ROUND(15) TF_ROUND(26) TF_ROUND(6)
  x0 += k2; x1 += k0 + 5u;
#undef TF_ROUND
  o0 = x0; o1 = x1;
}

// jax _uniform: bits>>9 | 0x3f800000, bitcast f32, minus 1.0
__device__ __forceinline__ float bits_to_uniform(uint32_t bits) {
  return __uint_as_float((bits >> 9) | 0x3f800000u) - 1.0f;
}

// partitionable-mode random bits at 64-bit flat index (hi=0 for our sizes):
// bits = o0 ^ o1 of threefry(key, (idx_hi, idx_lo))
__device__ __forceinline__ float jax_uniform_at(uint32_t k0, uint32_t k1, uint32_t idx) {
  uint32_t o0, o1;
  threefry2x32(k0, k1, 0u, idx, o0, o1);
  return bits_to_uniform(o0 ^ o1);
}

// ---------------- kernels ----------------
// ws layout: acc[0]=fwd_sum(fp*min_d), acc[1]=rev_sum(fp*d), ((int*)acc)[2]=max-bits
__global__ void init_kernel(float* acc) {
  int i = threadIdx.x;
  if (i < 8) acc[i] = 0.0f;  // 0 bits == 0.0f, valid init for positive-float max
}

// barycenters (+|.|^2 in w) for original faces, simplified faces; float4 vertices
__global__ __launch_bounds__(256) void prep_kernel(
    const float* __restrict__ ov, const int* __restrict__ ofc,
    const float* __restrict__ sv, const int* __restrict__ sfc,
    float4* __restrict__ ob4, float4* __restrict__ sb4, float4* __restrict__ ov4,
    int NOF, int NSF, int NOV) {
  int i = blockIdx.x * blockDim.x + threadIdx.x;
  int total = NOF + NSF + NOV;
  if (i >= total) return;
  if (i < NOF) {
    int a = ofc[3*i], b = ofc[3*i+1], c = ofc[3*i+2];
    float x = (ov[3*a]   + ov[3*b]   + ov[3*c])   / 3.0f;
    float y = (ov[3*a+1] + ov[3*b+1] + ov[3*c+1]) / 3.0f;
    float z = (ov[3*a+2] + ov[3*b+2] + ov[3*c+2]) / 3.0f;
    ob4[i] = make_float4(x, y, z, x*x + y*y + z*z);
  } else if (i < NOF + NSF) {
    int j = i - NOF;
    int a = sfc[3*j], b = sfc[3*j+1], c = sfc[3*j+2];
    float x = (sv[3*a]   + sv[3*b]   + sv[3*c])   / 3.0f;
    float y = (sv[3*a+1] + sv[3*b+1] + sv[3*c+1]) / 3.0f;
    float z = (sv[3*a+2] + sv[3*b+2] + sv[3*c+2]) / 3.0f;
    sb4[j] = make_float4(x, y, z, x*x + y*y + z*z);
  } else {
    int j = i - NOF - NSF;
    float x = ov[3*j], y = ov[3*j+1], z = ov[3*j+2];
    ov4[j] = make_float4(x, y, z, x*x + y*y + z*z);
  }
}

// forward: per simplified-face barycenter, min dist to original-face barycenters
#define FW_ROWS 8
#define FW_TILE 2000
__global__ __launch_bounds__(256) void forward_kernel(
    const float4* __restrict__ sb4, const float4* __restrict__ ob4,
    const float* __restrict__ fp, float* __restrict__ acc,
    int NSF, int NOF, int NFP) {
  __shared__ float4 tile[FW_TILE];
  int row  = blockIdx.x * FW_ROWS + (threadIdx.x >> 5);
  int lane = threadIdx.x & 31;
  bool valid = row < NSF;
  float4 s = make_float4(0.f, 0.f, 0.f, 0.f);
  if (valid) s = sb4[row];
  float m2x = -2.0f * s.x, m2y = -2.0f * s.y, m2z = -2.0f * s.z;
  float best = FLT_MAX;
  for (int t0 = 0; t0 < NOF; t0 += FW_TILE) {
    int n = min(FW_TILE, NOF - t0);
    __syncthreads();
    for (int j = threadIdx.x; j < n; j += 256) tile[j] = ob4[t0 + j];
    __syncthreads();
    for (int j = lane; j < n; j += 32) {
      float4 v = tile[j];
      float t = fmaf(v.z, m2z, fmaf(v.y, m2y, fmaf(v.x, m2x, v.w)));
      best = fminf(best, t);
    }
  }
  for (int o = 16; o > 0; o >>= 1)
    best = fminf(best, __shfl_down(best, o, 32));
  if (valid && lane == 0) {
    float mind = sqrtf(fmaxf(best + s.w, 0.0f));
    float p = (row < NFP) ? fp[row] : 0.0f;
    atomicAdd(&acc[0], p * mind);
  }
}

// reverse: generate sample (exact JAX RNG), brute-force 1-NN over all orig vertices
#define RV_TILE 2500
__global__ __launch_bounds__(256) void reverse_kernel(
    const float* __restrict__ sv, const int* __restrict__ sfc,
    const float* __restrict__ fp, const float4* __restrict__ ov4,
    float* __restrict__ acc, int NSF, int NOV, int NFP) {
  __shared__ float4 tile[RV_TILE];
  __shared__ float rsum[4], rmax[4];

  int sid = blockIdx.x * blockDim.x + threadIdx.x;
  int nsamp = NSF * NUM_SAMPLES;
  bool valid = sid < nsamp;
  int id = valid ? sid : 0;
  int face = id / NUM_SAMPLES;

  // split(key(42)) in foldlike (partitionable) mode:
  // rk_i = threefry((0,42), (0, i)), both output words
  uint32_t a0, a1, b0, b1;
  threefry2x32(0u, 42u, 0u, 0u, a0, a1);  // rk1
  threefry2x32(0u, 42u, 0u, 1u, b0, b1);  // rk2
  float r1 = jax_uniform_at(a0, a1, (uint32_t)id);
  float r2 = jax_uniform_at(b0, b1, (uint32_t)id);
  float sr1 = sqrtf(r1);
  float ca = 1.0f - sr1;
  float cb = sr1 * (1.0f - r2);
  float cc = sr1 * r2;

  int va = sfc[3*face], vb = sfc[3*face+1], vc = sfc[3*face+2];
  float px = ca*sv[3*va]   + cb*sv[3*vb]   + cc*sv[3*vc];
  float py = ca*sv[3*va+1] + cb*sv[3*vb+1] + cc*sv[3*vc+1];
  float pz = ca*sv[3*va+2] + cb*sv[3*vb+2] + cc*sv[3*vc+2];

  float p2  = px*px + py*py + pz*pz;
  float m2x = -2.0f*px, m2y = -2.0f*py, m2z = -2.0f*pz;

  float best0 = FLT_MAX, best1 = FLT_MAX;
  for (int t0 = 0; t0 < NOV; t0 += RV_TILE) {
    int n = min(RV_TILE, NOV - t0);
    __syncthreads();
    for (int j = threadIdx.x; j < n; j += 256) tile[j] = ov4[t0 + j];
    __syncthreads();
    int j = 0;
#pragma unroll 4
    for (; j + 1 < n; j += 2) {
      float4 v0 = tile[j];
      float4 v1 = tile[j + 1];
      float t0_ = fmaf(v0.z, m2z, fmaf(v0.y, m2y, fmaf(v0.x, m2x, v0.w)));
      float t1_ = fmaf(v1.z, m2z, fmaf(v1.y, m2y, fmaf(v1.x, m2x, v1.w)));
      best0 = fminf(best0, t0_);
      best1 = fminf(best1, t1_);
    }
    if (j < n) {
      float4 v0 = tile[j];
      best0 = fminf(best0, fmaf(v0.z, m2z, fmaf(v0.y, m2y, fmaf(v0.x, m2x, v0.w))));
    }
  }
  float best = fminf(best0, best1);
  float d = valid ? sqrtf(fmaxf(best + p2, 0.0f)) : 0.0f;
  float w = (valid && face < NFP) ? fp[face] : 0.0f;

  // block reduce: sum(w*d), max(d)
  float sv_ = w * d;
  float mv  = d;
  for (int o = 32; o > 0; o >>= 1) {
    sv_ += __shfl_down(sv_, o);
    mv = fmaxf(mv, __shfl_down(mv, o));
  }
  int wid = threadIdx.x >> 6;
  if ((threadIdx.x & 63) == 0) { rsum[wid] = sv_; rmax[wid] = mv; }
  __syncthreads();
  if (threadIdx.x == 0) {
    float ts = 0.0f, tm = 0.0f;
    for (int i = 0; i < 4; ++i) { ts += rsum[i]; tm = fmaxf(tm, rmax[i]); }
    atomicAdd(&acc[1], ts);
    atomicMax((int*)acc + 2, __float_as_int(tm));  // all d >= 0
  }
}

__global__ __launch_bounds__(256) void final_kernel(
    const float* __restrict__ fp, const float* __restrict__ acc,
    float* __restrict__ out, int NSF, int NFP) {
  __shared__ float red[256];
  float s = 0.0f;
  for (int i = threadIdx.x; i < NSF; i += 256)
    s += (i < NFP) ? fp[i] : 0.0f;
  red[threadIdx.x] = s;
  __syncthreads();
  for (int o = 128; o > 0; o >>= 1) {
    if (threadIdx.x < o) red[threadIdx.x] += red[threadIdx.x + o];
    __syncthreads();
  }
  if (threadIdx.x == 0) {
    float sum_fp = red[0];
    float fwd = acc[0] + PENALTY * ((float)NSF - sum_fp);
    float maxd = __int_as_float(((const int*)acc)[2]);
    float rev = acc[1] * (REV_SCALE / (maxd + EPSF));
    out[0] = fwd + rev;
  }
}

extern "C" void kernel_launch(void* const* d_in, const int* in_sizes, int n_in,
                              void* d_out, int out_size, void* d_ws, size_t ws_size,
                              hipStream_t stream) {
  const float* ov  = (const float*)d_in[0];
  const int*   ofc = (const int*)  d_in[1];
  const float* sv  = (const float*)d_in[2];
  const int*   sfc = (const int*)  d_in[3];
  const float* fp  = (const float*)d_in[4];
  float* out = (float*)d_out;

  int NOV = in_sizes[0] / 3;
  int NOF = in_sizes[1] / 3;
  int NSF = in_sizes[3] / 3;
  int NFP = in_sizes[4];

  float*  acc = (float*)d_ws;
  float4* ob4 = (float4*)((char*)d_ws + 256);
  float4* sb4 = ob4 + NOF;
  float4* ov4 = sb4 + NSF;

  hipLaunchKernelGGL(init_kernel, dim3(1), dim3(64), 0, stream, acc);

  int total = NOF + NSF + NOV;
  hipLaunchKernelGGL(prep_kernel, dim3((total + 255) / 256), dim3(256), 0, stream,
                     ov, ofc, sv, sfc, ob4, sb4, ov4, NOF, NSF, NOV);

  hipLaunchKernelGGL(forward_kernel, dim3((NSF + FW_ROWS - 1) / FW_ROWS), dim3(256), 0, stream,
                     sb4, ob4, fp, acc, NSF, NOF, NFP);

  int nsamp = NSF * NUM_SAMPLES;
  hipLaunchKernelGGL(reverse_kernel, dim3((nsamp + 255) / 256), dim3(256), 0, stream,
                     sv, sfc, fp, ov4, acc, NSF, NOV, NFP);

  hipLaunchKernelGGL(final_kernel, dim3(1), dim3(256), 0, stream, fp, acc, out, NSF, NFP);
}

// Round 2
// 787.643 us; speedup vs baseline: 1.0146x; 1.0146x over previous
//
#include <hip/hip_runtime.h>
#include <stdint.h>
#include <float.h>

#define NUM_SAMPLES 50
#define EPSF 1e-8f
#define PENALTY 1e-4f
#define REV_SCALE 0.1f

// grid 1: original vertices (N(0,1) coords)
#define G1 48
#define G1LO -5.0f
#define G1HI 5.0f
#define NCELL1 (G1*G1*G1)
// grid 2: original-face barycenters (sigma ~0.577)
#define G2 48
#define G2LO -3.5f
#define G2HI 3.5f
#define NCELL2 (G2*G2*G2)
#define NTOT (NCELL1 + NCELL2)

// ---------------- JAX threefry2x32 (exact) ----------------
__device__ __forceinline__ uint32_t rotl32(uint32_t v, int d) {
  return (v << d) | (v >> (32 - d));
}

__device__ __forceinline__ void threefry2x32(uint32_t k0, uint32_t k1,
                                             uint32_t x0, uint32_t x1,
                                             uint32_t& o0, uint32_t& o1) {
  const uint32_t k2 = k0 ^ k1 ^ 0x1BD11BDAu;
  x0 += k0; x1 += k1;
#define TF_ROUND(r) { x0 += x1; x1 = rotl32(x1, (r)); x1 ^= x0; }
  TF_ROUND(13) TF_ROUND(15) TF_ROUND(26) TF_ROUND(6)
  x0 += k1; x1 += k2 + 1u;
  TF_ROUND(17) TF_ROUND(29) TF_ROUND(16) TF_ROUND(24)
  x0 += k2; x1 += k0 + 2u;
  TF_ROUND(13) TF_ROUND(15) TF_ROUND(26) TF_ROUND(6)
  x0 += k0; x1 += k1 + 3u;
  TF_ROUND(17) TF_ROUND(29) TF_ROUND(16) TF_ROUND(24)
  x0 += k1; x1 += k2 + 4u;
  TF_ROUND(13) TF_ROUND(15) TF_ROUND(26) TF_ROUND(6)
  x0 += k2; x1 += k0 + 5u;
#undef TF_ROUND
  o0 = x0; o1 = x1;
}

__device__ __forceinline__ float bits_to_uniform(uint32_t bits) {
  return __uint_as_float((bits >> 9) | 0x3f800000u) - 1.0f;
}

__device__ __forceinline__ float jax_uniform_at(uint32_t k0, uint32_t k1, uint32_t idx) {
  uint32_t o0, o1;
  threefry2x32(k0, k1, 0u, idx, o0, o1);
  return bits_to_uniform(o0 ^ o1);
}

__device__ __forceinline__ int cell_coord(float p, float lo, float invh, int G) {
  int i = (int)floorf((p - lo) * invh);
  return min(max(i, 0), G - 1);
}

// ---------------- prep: init-free (memset done host-side), barycenters + histogram
__global__ __launch_bounds__(256) void prep_kernel(
    const float* __restrict__ ov, const int* __restrict__ ofc,
    const float* __restrict__ sv, const int* __restrict__ sfc,
    float4* __restrict__ ob4, float4* __restrict__ sb4, float4* __restrict__ ov4,
    int* __restrict__ cnt, int NOF, int NSF, int NOV) {
  int i = blockIdx.x * blockDim.x + threadIdx.x;
  int total = NOF + NSF + NOV;
  if (i >= total) return;
  if (i < NOF) {
    int a = ofc[3*i], b = ofc[3*i+1], c = ofc[3*i+2];
    float x = (ov[3*a]   + ov[3*b]   + ov[3*c])   / 3.0f;
    float y = (ov[3*a+1] + ov[3*b+1] + ov[3*c+1]) / 3.0f;
    float z = (ov[3*a+2] + ov[3*b+2] + ov[3*c+2]) / 3.0f;
    ob4[i] = make_float4(x, y, z, x*x + y*y + z*z);
    const float invh = (float)G2 / (G2HI - G2LO);
    int cx = cell_coord(x, G2LO, invh, G2);
    int cy = cell_coord(y, G2LO, invh, G2);
    int cz = cell_coord(z, G2LO, invh, G2);
    atomicAdd(&cnt[NCELL1 + (cz*G2 + cy)*G2 + cx], 1);
  } else if (i < NOF + NSF) {
    int j = i - NOF;
    int a = sfc[3*j], b = sfc[3*j+1], c = sfc[3*j+2];
    float x = (sv[3*a]   + sv[3*b]   + sv[3*c])   / 3.0f;
    float y = (sv[3*a+1] + sv[3*b+1] + sv[3*c+1]) / 3.0f;
    float z = (sv[3*a+2] + sv[3*b+2] + sv[3*c+2]) / 3.0f;
    sb4[j] = make_float4(x, y, z, x*x + y*y + z*z);
  } else {
    int j = i - NOF - NSF;
    float x = ov[3*j], y = ov[3*j+1], z = ov[3*j+2];
    ov4[j] = make_float4(x, y, z, x*x + y*y + z*z);
    const float invh = (float)G1 / (G1HI - G1LO);
    int cx = cell_coord(x, G1LO, invh, G1);
    int cy = cell_coord(y, G1LO, invh, G1);
    int cz = cell_coord(z, G1LO, invh, G1);
    atomicAdd(&cnt[(cz*G1 + cy)*G1 + cx], 1);
  }
}

// ---------------- single-block exclusive scan over NTOT cells
__global__ __launch_bounds__(1024) void scan_kernel(
    const int* __restrict__ cnt, int* __restrict__ cs, int* __restrict__ cur, int n) {
  __shared__ int part[1024];
  int t = threadIdx.x;
  int per = (n + 1023) >> 10;
  int beg = t * per;
  int end = min(beg + per, n);
  int s = 0;
  for (int i = beg; i < end; ++i) s += cnt[i];
  part[t] = s;
  __syncthreads();
  for (int d = 1; d < 1024; d <<= 1) {
    int v = (t >= d) ? part[t - d] : 0;
    __syncthreads();
    part[t] += v;
    __syncthreads();
  }
  int off = part[t] - s;  // exclusive
  for (int i = beg; i < end; ++i) {
    cs[i] = off; cur[i] = off;
    off += cnt[i];
  }
  if (end == n && beg <= n) cs[n] = off;
}

// ---------------- scatter points into sorted order
__global__ __launch_bounds__(256) void scatter_kernel(
    const float4* __restrict__ ov4, const float4* __restrict__ ob4,
    int* __restrict__ cur, float4* __restrict__ sorted, int NOV, int NOF) {
  int i = blockIdx.x * blockDim.x + threadIdx.x;
  if (i >= NOV + NOF) return;
  float4 p; int c;
  if (i < NOV) {
    p = ov4[i];
    const float invh = (float)G1 / (G1HI - G1LO);
    int cx = cell_coord(p.x, G1LO, invh, G1);
    int cy = cell_coord(p.y, G1LO, invh, G1);
    int cz = cell_coord(p.z, G1LO, invh, G1);
    c = (cz*G1 + cy)*G1 + cx;
  } else {
    p = ob4[i - NOV];
    const float invh = (float)G2 / (G2HI - G2LO);
    int cx = cell_coord(p.x, G2LO, invh, G2);
    int cy = cell_coord(p.y, G2LO, invh, G2);
    int cz = cell_coord(p.z, G2LO, invh, G2);
    c = NCELL1 + (cz*G2 + cy)*G2 + cx;
  }
  int idx = atomicAdd(&cur[c], 1);
  sorted[idx] = p;
}

// ---------------- exact 1-NN via ring expansion; returns t = d^2 - q2
__device__ float nn_best_t(float px, float py, float pz, float q2,
                           const int* __restrict__ cs, const float4* __restrict__ pts,
                           int G, float lo, float h, int cellofs) {
  const float invh = 1.0f / h;
  int ix = cell_coord(px, lo, invh, G);
  int iy = cell_coord(py, lo, invh, G);
  int iz = cell_coord(pz, lo, invh, G);
  float m2x = -2.0f*px, m2y = -2.0f*py, m2z = -2.0f*pz;
  float best = FLT_MAX;
  for (int r = 0; r < G; ++r) {
    if (r >= 1) {
      float bd = (float)(r - 1) * h;
      if (best + q2 <= bd * bd) break;  // d^2 <= ring lower bound^2 -> done
    }
    int z0 = max(iz - r, 0), z1 = min(iz + r, G - 1);
    int y0 = max(iy - r, 0), y1 = min(iy + r, G - 1);
    int x0 = max(ix - r, 0), x1 = min(ix + r, G - 1);
    for (int zz = z0; zz <= z1; ++zz) {
      int adz = abs(zz - iz);
      for (int yy = y0; yy <= y1; ++yy) {
        int ady = abs(yy - iy);
        int rowbase = cellofs + (zz*G + yy)*G;
        if (adz == r || ady == r) {
          int s = cs[rowbase + x0];
          int e = cs[rowbase + x1 + 1];
          for (int i = s; i < e; ++i) {
            float4 v = pts[i];
            float t = fmaf(v.z, m2z, fmaf(v.y, m2y, fmaf(v.x, m2x, v.w)));
            best = fminf(best, t);
          }
        } else {
          if (ix - r >= 0) {
            int c = rowbase + ix - r;
            int s = cs[c], e = cs[c + 1];
            for (int i = s; i < e; ++i) {
              float4 v = pts[i];
              float t = fmaf(v.z, m2z, fmaf(v.y, m2y, fmaf(v.x, m2x, v.w)));
              best = fminf(best, t);
            }
          }
          if (r > 0 && ix + r <= G - 1) {
            int c = rowbase + ix + r;
            int s = cs[c], e = cs[c + 1];
            for (int i = s; i < e; ++i) {
              float4 v = pts[i];
              float t = fmaf(v.z, m2z, fmaf(v.y, m2y, fmaf(v.x, m2x, v.w)));
              best = fminf(best, t);
            }
          }
        }
      }
    }
  }
  return best;
}

// ---------------- fused queries: forward blocks then reverse blocks
__global__ __launch_bounds__(256) void query_kernel(
    const float* __restrict__ sv, const int* __restrict__ sfc,
    const float* __restrict__ fp, const float4* __restrict__ sb4,
    const int* __restrict__ cs, const float4* __restrict__ sorted,
    float* __restrict__ acc, int NSF, int NFP, int fwdBlocks) {
  __shared__ float rsum[4], rmax[4];
  int bid = blockIdx.x;
  const float h1 = (G1HI - G1LO) / (float)G1;
  const float h2 = (G2HI - G2LO) / (float)G2;

  if (bid < fwdBlocks) {
    // forward: simplified barycenter -> nearest original barycenter
    int i = bid * blockDim.x + threadIdx.x;
    float contrib = 0.0f;
    if (i < NSF) {
      float4 s = sb4[i];
      float best = nn_best_t(s.x, s.y, s.z, s.w, cs, sorted, G2, G2LO, h2, NCELL1);
      float mind = sqrtf(fmaxf(best + s.w, 0.0f));
      float p = (i < NFP) ? fp[i] : 0.0f;
      contrib = p * mind;
    }
    for (int o = 32; o > 0; o >>= 1) contrib += __shfl_down(contrib, o);
    int wid = threadIdx.x >> 6;
    if ((threadIdx.x & 63) == 0) rsum[wid] = contrib;
    __syncthreads();
    if (threadIdx.x == 0) {
      float ts = rsum[0] + rsum[1] + rsum[2] + rsum[3];
      atomicAdd(&acc[0], ts);
    }
  } else {
    // reverse: sample on simplified faces -> nearest original vertex
    int sid = (bid - fwdBlocks) * blockDim.x + threadIdx.x;
    int nsamp = NSF * NUM_SAMPLES;
    bool valid = sid < nsamp;
    int id = valid ? sid : 0;
    int face = id / NUM_SAMPLES;

    uint32_t a0, a1, b0, b1;
    threefry2x32(0u, 42u, 0u, 0u, a0, a1);  // rk1 = split(key(42))[0]
    threefry2x32(0u, 42u, 0u, 1u, b0, b1);  // rk2 = split(key(42))[1]
    float r1 = jax_uniform_at(a0, a1, (uint32_t)id);
    float r2 = jax_uniform_at(b0, b1, (uint32_t)id);
    float sr1 = sqrtf(r1);
    float ca = 1.0f - sr1;
    float cb = sr1 * (1.0f - r2);
    float cc = sr1 * r2;

    int va = sfc[3*face], vb = sfc[3*face+1], vc = sfc[3*face+2];
    float px = ca*sv[3*va]   + cb*sv[3*vb]   + cc*sv[3*vc];
    float py = ca*sv[3*va+1] + cb*sv[3*vb+1] + cc*sv[3*vc+1];
    float pz = ca*sv[3*va+2] + cb*sv[3*vb+2] + cc*sv[3*vc+2];
    float q2 = px*px + py*py + pz*pz;

    float best = nn_best_t(px, py, pz, q2, cs, sorted, G1, G1LO, h1, 0);
    float d = valid ? sqrtf(fmaxf(best + q2, 0.0f)) : 0.0f;
    float w = (valid && face < NFP) ? fp[face] : 0.0f;

    float sv_ = w * d;
    float mv  = d;
    for (int o = 32; o > 0; o >>= 1) {
      sv_ += __shfl_down(sv_, o);
      mv = fmaxf(mv, __shfl_down(mv, o));
    }
    int wid = threadIdx.x >> 6;
    if ((threadIdx.x & 63) == 0) { rsum[wid] = sv_; rmax[wid] = mv; }
    __syncthreads();
    if (threadIdx.x == 0) {
      float ts = 0.0f, tm = 0.0f;
      for (int i = 0; i < 4; ++i) { ts += rsum[i]; tm = fmaxf(tm, rmax[i]); }
      atomicAdd(&acc[1], ts);
      atomicMax((int*)acc + 2, __float_as_int(tm));  // all d >= 0
    }
  }
}

__global__ __launch_bounds__(256) void final_kernel(
    const float* __restrict__ fp, const float* __restrict__ acc,
    float* __restrict__ out, int NSF, int NFP) {
  __shared__ float red[256];
  float s = 0.0f;
  for (int i = threadIdx.x; i < NSF; i += 256)
    s += (i < NFP) ? fp[i] : 0.0f;
  red[threadIdx.x] = s;
  __syncthreads();
  for (int o = 128; o > 0; o >>= 1) {
    if (threadIdx.x < o) red[threadIdx.x] += red[threadIdx.x + o];
    __syncthreads();
  }
  if (threadIdx.x == 0) {
    float sum_fp = red[0];
    float fwd = acc[0] + PENALTY * ((float)NSF - sum_fp);
    float maxd = __int_as_float(((const int*)acc)[2]);
    float rev = acc[1] * (REV_SCALE / (maxd + EPSF));
    out[0] = fwd + rev;
  }
}

extern "C" void kernel_launch(void* const* d_in, const int* in_sizes, int n_in,
                              void* d_out, int out_size, void* d_ws, size_t ws_size,
                              hipStream_t stream) {
  const float* ov  = (const float*)d_in[0];
  const int*   ofc = (const int*)  d_in[1];
  const float* sv  = (const float*)d_in[2];
  const int*   sfc = (const int*)  d_in[3];
  const float* fp  = (const float*)d_in[4];
  float* out = (float*)d_out;

  int NOV = in_sizes[0] / 3;
  int NOF = in_sizes[1] / 3;
  int NSF = in_sizes[3] / 3;
  int NFP = in_sizes[4];

  // ws layout
  char* w = (char*)d_ws;
  float*  acc    = (float*)w;              w += 256;
  float4* ob4    = (float4*)w;             w += (size_t)NOF * 16;
  float4* sb4    = (float4*)w;             w += (size_t)NSF * 16;
  float4* ov4    = (float4*)w;             w += (size_t)NOV * 16;
  float4* sorted = (float4*)w;             w += (size_t)(NOV + NOF) * 16;
  int*    cnt    = (int*)w;                w += (size_t)NTOT * 4;
  int*    cs     = (int*)w;                w += (size_t)(NTOT + 1) * 4;
  int*    cur    = (int*)w;                w += (size_t)NTOT * 4;

  hipMemsetAsync(acc, 0, 256, stream);
  hipMemsetAsync(cnt, 0, (size_t)NTOT * 4, stream);

  int total = NOF + NSF + NOV;
  hipLaunchKernelGGL(prep_kernel, dim3((total + 255) / 256), dim3(256), 0, stream,
                     ov, ofc, sv, sfc, ob4, sb4, ov4, cnt, NOF, NSF, NOV);

  hipLaunchKernelGGL(scan_kernel, dim3(1), dim3(1024), 0, stream, cnt, cs, cur, NTOT);

  hipLaunchKernelGGL(scatter_kernel, dim3((NOV + NOF + 255) / 256), dim3(256), 0, stream,
                     ov4, ob4, cur, sorted, NOV, NOF);

  int fwdBlocks = (NSF + 255) / 256;
  int revBlocks = (NSF * NUM_SAMPLES + 255) / 256;
  hipLaunchKernelGGL(query_kernel, dim3(fwdBlocks + revBlocks), dim3(256), 0, stream,
                     sv, sfc, fp, sb4, cs, sorted, acc, NSF, NFP, fwdBlocks);

  hipLaunchKernelGGL(final_kernel, dim3(1), dim3(256), 0, stream, fp, acc, out, NSF, NFP);
}

// Round 3
// 391.960 us; speedup vs baseline: 2.0388x; 2.0095x over previous
//
#include <hip/hip_runtime.h>
#include <stdint.h>
#include <float.h>

#define NUM_SAMPLES 50
#define EPSF 1e-8f
#define PENALTY 1e-4f
#define REV_SCALE 0.1f

// grid 1: original vertices (N(0,1) coords)
#define G1 48
#define G1LO -5.0f
#define G1HI 5.0f
#define NCELL1 (G1*G1*G1)
// grid 2: original-face barycenters (sigma ~0.577)
#define G2 48
#define G2LO -3.5f
#define G2HI 3.5f
#define NCELL2 (G2*G2*G2)
// grid 3: sample-point buckets (query sorting only)
#define G3 32
#define G3LO -5.0f
#define G3HI 5.0f
#define NCELL3 (G3*G3*G3)

#define NTOTALL (NCELL1 + NCELL2 + NCELL3)   // 253952
#define SCAN_BLOCKS (NTOTALL / 1024)          // 248
static_assert(NTOTALL % 1024 == 0, "scan tiling");

// ---------------- JAX threefry2x32 (exact) ----------------
__device__ __forceinline__ uint32_t rotl32(uint32_t v, int d) {
  return (v << d) | (v >> (32 - d));
}

__device__ __forceinline__ void threefry2x32(uint32_t k0, uint32_t k1,
                                             uint32_t x0, uint32_t x1,
                                             uint32_t& o0, uint32_t& o1) {
  const uint32_t k2 = k0 ^ k1 ^ 0x1BD11BDAu;
  x0 += k0; x1 += k1;
#define TF_ROUND(r) { x0 += x1; x1 = rotl32(x1, (r)); x1 ^= x0; }
  TF_ROUND(13) TF_ROUND(15) TF_ROUND(26) TF_ROUND(6)
  x0 += k1; x1 += k2 + 1u;
  TF_ROUND(17) TF_ROUND(29) TF_ROUND(16) TF_ROUND(24)
  x0 += k2; x1 += k0 + 2u;
  TF_ROUND(13) TF_ROUND(15) TF_ROUND(26) TF_ROUND(6)
  x0 += k0; x1 += k1 + 3u;
  TF_ROUND(17) TF_ROUND(29) TF_ROUND(16) TF_ROUND(24)
  x0 += k1; x1 += k2 + 4u;
  TF_ROUND(13) TF_ROUND(15) TF_ROUND(26) TF_ROUND(6)
  x0 += k2; x1 += k0 + 5u;
#undef TF_ROUND
  o0 = x0; o1 = x1;
}

__device__ __forceinline__ float bits_to_uniform(uint32_t bits) {
  return __uint_as_float((bits >> 9) | 0x3f800000u) - 1.0f;
}

__device__ __forceinline__ float jax_uniform_at(uint32_t k0, uint32_t k1, uint32_t idx) {
  uint32_t o0, o1;
  threefry2x32(k0, k1, 0u, idx, o0, o1);
  return bits_to_uniform(o0 ^ o1);
}

__device__ __forceinline__ int cell_coord(float p, float lo, float invh, int G) {
  int i = (int)floorf((p - lo) * invh);
  return min(max(i, 0), G - 1);
}

// sample id -> position + weight (exact JAX RNG; partitionable split of key(42))
__device__ __forceinline__ float4 gen_sample(int id, const float* __restrict__ sv,
                                             const int* __restrict__ sfc,
                                             const float* __restrict__ fp, int NFP) {
  int face = id / NUM_SAMPLES;
  uint32_t a0, a1, b0, b1;
  threefry2x32(0u, 42u, 0u, 0u, a0, a1);  // rk1
  threefry2x32(0u, 42u, 0u, 1u, b0, b1);  // rk2
  float r1 = jax_uniform_at(a0, a1, (uint32_t)id);
  float r2 = jax_uniform_at(b0, b1, (uint32_t)id);
  float sr1 = sqrtf(r1);
  float ca = 1.0f - sr1;
  float cb = sr1 * (1.0f - r2);
  float cc = sr1 * r2;
  int va = sfc[3*face], vb = sfc[3*face+1], vc = sfc[3*face+2];
  float px = ca*sv[3*va]   + cb*sv[3*vb]   + cc*sv[3*vc];
  float py = ca*sv[3*va+1] + cb*sv[3*vb+1] + cc*sv[3*vc+1];
  float pz = ca*sv[3*va+2] + cb*sv[3*vb+2] + cc*sv[3*vc+2];
  float w = (face < NFP) ? fp[face] : 0.0f;
  return make_float4(px, py, pz, w);
}

// ---------------- prep: barycenters + vertex float4 + histograms (3 grids)
__global__ __launch_bounds__(256) void prep_kernel(
    const float* __restrict__ ov, const int* __restrict__ ofc,
    const float* __restrict__ sv, const int* __restrict__ sfc,
    const float* __restrict__ fp,
    float4* __restrict__ ob4, float4* __restrict__ sb4, float4* __restrict__ ov4,
    int* __restrict__ cnt, int NOF, int NSF, int NOV, int NFP, int nsamp) {
  int i = blockIdx.x * blockDim.x + threadIdx.x;
  int total = NOF + NSF + NOV + nsamp;
  if (i >= total) return;
  if (i < NOF) {
    int a = ofc[3*i], b = ofc[3*i+1], c = ofc[3*i+2];
    float x = (ov[3*a]   + ov[3*b]   + ov[3*c])   / 3.0f;
    float y = (ov[3*a+1] + ov[3*b+1] + ov[3*c+1]) / 3.0f;
    float z = (ov[3*a+2] + ov[3*b+2] + ov[3*c+2]) / 3.0f;
    ob4[i] = make_float4(x, y, z, x*x + y*y + z*z);
    const float invh = (float)G2 / (G2HI - G2LO);
    int cx = cell_coord(x, G2LO, invh, G2);
    int cy = cell_coord(y, G2LO, invh, G2);
    int cz = cell_coord(z, G2LO, invh, G2);
    atomicAdd(&cnt[NCELL1 + (cz*G2 + cy)*G2 + cx], 1);
  } else if (i < NOF + NSF) {
    int j = i - NOF;
    int a = sfc[3*j], b = sfc[3*j+1], c = sfc[3*j+2];
    float x = (sv[3*a]   + sv[3*b]   + sv[3*c])   / 3.0f;
    float y = (sv[3*a+1] + sv[3*b+1] + sv[3*c+1]) / 3.0f;
    float z = (sv[3*a+2] + sv[3*b+2] + sv[3*c+2]) / 3.0f;
    sb4[j] = make_float4(x, y, z, x*x + y*y + z*z);
  } else if (i < NOF + NSF + NOV) {
    int j = i - NOF - NSF;
    float x = ov[3*j], y = ov[3*j+1], z = ov[3*j+2];
    ov4[j] = make_float4(x, y, z, x*x + y*y + z*z);
    const float invh = (float)G1 / (G1HI - G1LO);
    int cx = cell_coord(x, G1LO, invh, G1);
    int cy = cell_coord(y, G1LO, invh, G1);
    int cz = cell_coord(z, G1LO, invh, G1);
    atomicAdd(&cnt[(cz*G1 + cy)*G1 + cx], 1);
  } else {
    int j = i - NOF - NSF - NOV;
    float4 s = gen_sample(j, sv, sfc, fp, NFP);
    const float invh = (float)G3 / (G3HI - G3LO);
    int cx = cell_coord(s.x, G3LO, invh, G3);
    int cy = cell_coord(s.y, G3LO, invh, G3);
    int cz = cell_coord(s.z, G3LO, invh, G3);
    atomicAdd(&cnt[NCELL1 + NCELL2 + (cz*G3 + cy)*G3 + cx], 1);
  }
}

// ---------------- parallel scan: a) block sums, b) scan block sums, c) apply
__global__ __launch_bounds__(256) void scan_a_kernel(
    const int4* __restrict__ cnt4, int* __restrict__ bsum) {
  __shared__ int wsum[4];
  int t = threadIdx.x;
  int4 c = cnt4[blockIdx.x * 256 + t];
  int s = c.x + c.y + c.z + c.w;
  for (int o = 32; o > 0; o >>= 1) s += __shfl_down(s, o);
  if ((t & 63) == 0) wsum[t >> 6] = s;
  __syncthreads();
  if (t == 0) bsum[blockIdx.x] = wsum[0] + wsum[1] + wsum[2] + wsum[3];
}

__global__ __launch_bounds__(256) void scan_b_kernel(
    const int* __restrict__ bsum, int* __restrict__ boff, int* __restrict__ cs, int nblk, int ntot) {
  __shared__ int part[256];
  int t = threadIdx.x;
  int v = (t < nblk) ? bsum[t] : 0;
  part[t] = v;
  __syncthreads();
  for (int d = 1; d < 256; d <<= 1) {
    int u = (t >= d) ? part[t - d] : 0;
    __syncthreads();
    part[t] += u;
    __syncthreads();
  }
  if (t < nblk) boff[t] = part[t] - v;       // exclusive
  if (t == nblk - 1) cs[ntot] = part[t];     // total
}

__global__ __launch_bounds__(256) void scan_c_kernel(
    const int4* __restrict__ cnt4, const int* __restrict__ boff,
    int4* __restrict__ cs4, int4* __restrict__ cur4) {
  __shared__ int lds[256];
  int t = threadIdx.x;
  int gid = blockIdx.x * 256 + t;
  int4 c = cnt4[gid];
  int s01 = c.x + c.y;
  int tsum = s01 + c.z + c.w;
  lds[t] = tsum;
  __syncthreads();
  for (int d = 1; d < 256; d <<= 1) {
    int u = (t >= d) ? lds[t - d] : 0;
    __syncthreads();
    lds[t] += u;
    __syncthreads();
  }
  int base = boff[blockIdx.x] + lds[t] - tsum;
  int4 o;
  o.x = base;
  o.y = base + c.x;
  o.z = base + s01;
  o.w = base + s01 + c.z;
  cs4[gid] = o;
  cur4[gid] = o;
}

// ---------------- scatter points + samples into cell-sorted order
__global__ __launch_bounds__(256) void scatter_kernel(
    const float4* __restrict__ ov4, const float4* __restrict__ ob4,
    const float* __restrict__ sv, const int* __restrict__ sfc,
    const float* __restrict__ fp,
    int* __restrict__ cur, float4* __restrict__ sorted,
    int NOV, int NOF, int NFP, int nsamp) {
  int i = blockIdx.x * blockDim.x + threadIdx.x;
  if (i >= NOV + NOF + nsamp) return;
  float4 p; int c;
  if (i < NOV) {
    p = ov4[i];
    const float invh = (float)G1 / (G1HI - G1LO);
    int cx = cell_coord(p.x, G1LO, invh, G1);
    int cy = cell_coord(p.y, G1LO, invh, G1);
    int cz = cell_coord(p.z, G1LO, invh, G1);
    c = (cz*G1 + cy)*G1 + cx;
  } else if (i < NOV + NOF) {
    p = ob4[i - NOV];
    const float invh = (float)G2 / (G2HI - G2LO);
    int cx = cell_coord(p.x, G2LO, invh, G2);
    int cy = cell_coord(p.y, G2LO, invh, G2);
    int cz = cell_coord(p.z, G2LO, invh, G2);
    c = NCELL1 + (cz*G2 + cy)*G2 + cx;
  } else {
    int j = i - NOV - NOF;
    p = gen_sample(j, sv, sfc, fp, NFP);   // regenerate (saves a 4 MB staging array)
    const float invh = (float)G3 / (G3HI - G3LO);
    int cx = cell_coord(p.x, G3LO, invh, G3);
    int cy = cell_coord(p.y, G3LO, invh, G3);
    int cz = cell_coord(p.z, G3LO, invh, G3);
    c = NCELL1 + NCELL2 + (cz*G3 + cy)*G3 + cx;
  }
  int idx = atomicAdd(&cur[c], 1);
  sorted[idx] = p;
}

// ---------------- exact 1-NN via ring expansion; returns t = d^2 - q2
__device__ float nn_best_t(float px, float py, float pz, float q2,
                           const int* __restrict__ cs, const float4* __restrict__ pts,
                           int G, float lo, float h, int cellofs) {
  const float invh = 1.0f / h;
  int ix = cell_coord(px, lo, invh, G);
  int iy = cell_coord(py, lo, invh, G);
  int iz = cell_coord(pz, lo, invh, G);
  float m2x = -2.0f*px, m2y = -2.0f*py, m2z = -2.0f*pz;
  float best = FLT_MAX;
  for (int r = 0; r < G; ++r) {
    if (r >= 1) {
      float bd = (float)(r - 1) * h;
      if (best + q2 <= bd * bd) break;  // d^2 <= ring lower bound^2 -> done
    }
    int z0 = max(iz - r, 0), z1 = min(iz + r, G - 1);
    int y0 = max(iy - r, 0), y1 = min(iy + r, G - 1);
    int x0 = max(ix - r, 0), x1 = min(ix + r, G - 1);
    for (int zz = z0; zz <= z1; ++zz) {
      int adz = abs(zz - iz);
      for (int yy = y0; yy <= y1; ++yy) {
        int ady = abs(yy - iy);
        int rowbase = cellofs + (zz*G + yy)*G;
        if (adz == r || ady == r) {
          int s = cs[rowbase + x0];
          int e = cs[rowbase + x1 + 1];
          for (int i = s; i < e; ++i) {
            float4 v = pts[i];
            float t = fmaf(v.z, m2z, fmaf(v.y, m2y, fmaf(v.x, m2x, v.w)));
            best = fminf(best, t);
          }
        } else {
          if (ix - r >= 0) {
            int cc = rowbase + ix - r;
            int s = cs[cc], e = cs[cc + 1];
            for (int i = s; i < e; ++i) {
              float4 v = pts[i];
              float t = fmaf(v.z, m2z, fmaf(v.y, m2y, fmaf(v.x, m2x, v.w)));
              best = fminf(best, t);
            }
          }
          if (r > 0 && ix + r <= G - 1) {
            int cc = rowbase + ix + r;
            int s = cs[cc], e = cs[cc + 1];
            for (int i = s; i < e; ++i) {
              float4 v = pts[i];
              float t = fmaf(v.z, m2z, fmaf(v.y, m2y, fmaf(v.x, m2x, v.w)));
              best = fminf(best, t);
            }
          }
        }
      }
    }
  }
  return best;
}

// ---------------- fused queries: forward blocks then (sorted) reverse blocks
__global__ __launch_bounds__(256) void query_kernel(
    const float* __restrict__ fp, const float4* __restrict__ sb4,
    const int* __restrict__ cs, const float4* __restrict__ sorted,
    float* __restrict__ acc, int NSF, int NFP, int nsamp, int sampBase, int fwdBlocks) {
  __shared__ float rsum[4], rmax[4];
  int bid = blockIdx.x;
  const float h1 = (G1HI - G1LO) / (float)G1;
  const float h2 = (G2HI - G2LO) / (float)G2;

  if (bid < fwdBlocks) {
    int i = bid * blockDim.x + threadIdx.x;
    float contrib = 0.0f;
    if (i < NSF) {
      float4 s = sb4[i];
      float best = nn_best_t(s.x, s.y, s.z, s.w, cs, sorted, G2, G2LO, h2, NCELL1);
      float mind = sqrtf(fmaxf(best + s.w, 0.0f));
      float p = (i < NFP) ? fp[i] : 0.0f;
      contrib = p * mind;
    }
    for (int o = 32; o > 0; o >>= 1) contrib += __shfl_down(contrib, o);
    int wid = threadIdx.x >> 6;
    if ((threadIdx.x & 63) == 0) rsum[wid] = contrib;
    __syncthreads();
    if (threadIdx.x == 0)
      atomicAdd(&acc[0], rsum[0] + rsum[1] + rsum[2] + rsum[3]);
  } else {
    int sid = (bid - fwdBlocks) * blockDim.x + threadIdx.x;
    bool valid = sid < nsamp;
    float4 s = make_float4(0.f, 0.f, 0.f, 0.f);
    if (valid) s = sorted[sampBase + sid];
    float q2 = s.x*s.x + s.y*s.y + s.z*s.z;
    float d = 0.0f;
    if (valid) {
      float best = nn_best_t(s.x, s.y, s.z, q2, cs, sorted, G1, G1LO, h1, 0);
      d = sqrtf(fmaxf(best + q2, 0.0f));
    }
    float sv_ = s.w * d;
    float mv  = d;
    for (int o = 32; o > 0; o >>= 1) {
      sv_ += __shfl_down(sv_, o);
      mv = fmaxf(mv, __shfl_down(mv, o));
    }
    int wid = threadIdx.x >> 6;
    if ((threadIdx.x & 63) == 0) { rsum[wid] = sv_; rmax[wid] = mv; }
    __syncthreads();
    if (threadIdx.x == 0) {
      float ts = 0.0f, tm = 0.0f;
      for (int i = 0; i < 4; ++i) { ts += rsum[i]; tm = fmaxf(tm, rmax[i]); }
      atomicAdd(&acc[1], ts);
      atomicMax((int*)acc + 2, __float_as_int(tm));  // all d >= 0
    }
  }
}

__global__ __launch_bounds__(256) void final_kernel(
    const float* __restrict__ fp, const float* __restrict__ acc,
    float* __restrict__ out, int NSF, int NFP) {
  __shared__ float red[256];
  float s = 0.0f;
  for (int i = threadIdx.x; i < NSF; i += 256)
    s += (i < NFP) ? fp[i] : 0.0f;
  red[threadIdx.x] = s;
  __syncthreads();
  for (int o = 128; o > 0; o >>= 1) {
    if (threadIdx.x < o) red[threadIdx.x] += red[threadIdx.x + o];
    __syncthreads();
  }
  if (threadIdx.x == 0) {
    float sum_fp = red[0];
    float fwd = acc[0] + PENALTY * ((float)NSF - sum_fp);
    float maxd = __int_as_float(((const int*)acc)[2]);
    float rev = acc[1] * (REV_SCALE / (maxd + EPSF));
    out[0] = fwd + rev;
  }
}

extern "C" void kernel_launch(void* const* d_in, const int* in_sizes, int n_in,
                              void* d_out, int out_size, void* d_ws, size_t ws_size,
                              hipStream_t stream) {
  const float* ov  = (const float*)d_in[0];
  const int*   ofc = (const int*)  d_in[1];
  const float* sv  = (const float*)d_in[2];
  const int*   sfc = (const int*)  d_in[3];
  const float* fp  = (const float*)d_in[4];
  float* out = (float*)d_out;

  int NOV = in_sizes[0] / 3;
  int NOF = in_sizes[1] / 3;
  int NSF = in_sizes[3] / 3;
  int NFP = in_sizes[4];
  int nsamp = NSF * NUM_SAMPLES;

  // ws layout (all regions 16B-aligned)
  char* w = (char*)d_ws;
  float*  acc    = (float*)w;   w += 256;
  float4* ob4    = (float4*)w;  w += (size_t)NOF * 16;
  float4* sb4    = (float4*)w;  w += (size_t)NSF * 16;
  float4* ov4    = (float4*)w;  w += (size_t)NOV * 16;
  float4* sorted = (float4*)w;  w += (size_t)(NOV + NOF + nsamp) * 16;
  int*    cnt    = (int*)w;     w += (size_t)NTOTALL * 4;
  int*    cs     = (int*)w;     w += (size_t)(NTOTALL + 16) * 4;
  int*    cur    = (int*)w;     w += (size_t)NTOTALL * 4;
  int*    bsum   = (int*)w;     w += 1024;
  int*    boff   = (int*)w;     w += 1024;

  hipMemsetAsync(acc, 0, 256, stream);
  hipMemsetAsync(cnt, 0, (size_t)NTOTALL * 4, stream);

  int total = NOF + NSF + NOV + nsamp;
  hipLaunchKernelGGL(prep_kernel, dim3((total + 255) / 256), dim3(256), 0, stream,
                     ov, ofc, sv, sfc, fp, ob4, sb4, ov4, cnt, NOF, NSF, NOV, NFP, nsamp);

  hipLaunchKernelGGL(scan_a_kernel, dim3(SCAN_BLOCKS), dim3(256), 0, stream,
                     (const int4*)cnt, bsum);
  hipLaunchKernelGGL(scan_b_kernel, dim3(1), dim3(256), 0, stream,
                     bsum, boff, cs, SCAN_BLOCKS, NTOTALL);
  hipLaunchKernelGGL(scan_c_kernel, dim3(SCAN_BLOCKS), dim3(256), 0, stream,
                     (const int4*)cnt, boff, (int4*)cs, (int4*)cur);

  hipLaunchKernelGGL(scatter_kernel, dim3((NOV + NOF + nsamp + 255) / 256), dim3(256), 0, stream,
                     ov4, ob4, sv, sfc, fp, cur, sorted, NOV, NOF, NFP, nsamp);

  int fwdBlocks = (NSF + 255) / 256;
  int revBlocks = (nsamp + 255) / 256;
  hipLaunchKernelGGL(query_kernel, dim3(fwdBlocks + revBlocks), dim3(256), 0, stream,
                     fp, sb4, cs, sorted, acc, NSF, NFP, nsamp, NOV + NOF, fwdBlocks);

  hipLaunchKernelGGL(final_kernel, dim3(1), dim3(256), 0, stream, fp, acc, out, NSF, NFP);
}

// Round 4
// 360.123 us; speedup vs baseline: 2.2190x; 1.0884x over previous
//
#include <hip/hip_runtime.h>
#include <stdint.h>
#include <float.h>

#define NUM_SAMPLES 50
#define EPSF 1e-8f
#define PENALTY 1e-4f
#define REV_SCALE 0.1f

// grid 1: original vertices (N(0,1) coords)
#define G1 48
#define G1LO -5.0f
#define G1HI 5.0f
#define NCELL1 (G1*G1*G1)
// grid 2: original-face barycenters (sigma ~0.577)
#define G2 48
#define G2LO -3.5f
#define G2HI 3.5f
#define NCELL2 (G2*G2*G2)
// grid 3: sample-point buckets (query sorting only)
#define G3 32
#define G3LO -5.0f
#define G3HI 5.0f
#define NCELL3 (G3*G3*G3)

#define NTOTALL (NCELL1 + NCELL2 + NCELL3)   // 253952
#define SCAN_BLOCKS (NTOTALL / 1024)         // 248
static_assert(NTOTALL % 1024 == 0, "scan tiling");

#define GS 16          // lanes per query group
#define QBLOCKS 2048   // query kernel grid

// acc region layout (floats): fwd slots [0..1023] stride 16; rev slots [1024..2047];
// max slots (int bits) [2048..3071]; done counter (int) at [3072]. 4096 floats = 16 KB.
#define ACC_FLOATS 4096

// ---------------- JAX threefry2x32 (exact) ----------------
__device__ __forceinline__ uint32_t rotl32(uint32_t v, int d) {
  return (v << d) | (v >> (32 - d));
}

__device__ __forceinline__ void threefry2x32(uint32_t k0, uint32_t k1,
                                             uint32_t x0, uint32_t x1,
                                             uint32_t& o0, uint32_t& o1) {
  const uint32_t k2 = k0 ^ k1 ^ 0x1BD11BDAu;
  x0 += k0; x1 += k1;
#define TF_ROUND(r) { x0 += x1; x1 = rotl32(x1, (r)); x1 ^= x0; }
  TF_ROUND(13) TF_ROUND(15) TF_ROUND(26) TF_ROUND(6)
  x0 += k1; x1 += k2 + 1u;
  TF_ROUND(17) TF_ROUND(29) TF_ROUND(16) TF_ROUND(24)
  x0 += k2; x1 += k0 + 2u;
  TF_ROUND(13) TF_ROUND(15) TF_ROUND(26) TF_ROUND(6)
  x0 += k0; x1 += k1 + 3u;
  TF_ROUND(17) TF_ROUND(29) TF_ROUND(16) TF_ROUND(24)
  x0 += k1; x1 += k2 + 4u;
  TF_ROUND(13) TF_ROUND(15) TF_ROUND(26) TF_ROUND(6)
  x0 += k2; x1 += k0 + 5u;
#undef TF_ROUND
  o0 = x0; o1 = x1;
}

__device__ __forceinline__ float bits_to_uniform(uint32_t bits) {
  return __uint_as_float((bits >> 9) | 0x3f800000u) - 1.0f;
}

__device__ __forceinline__ float jax_uniform_at(uint32_t k0, uint32_t k1, uint32_t idx) {
  uint32_t o0, o1;
  threefry2x32(k0, k1, 0u, idx, o0, o1);
  return bits_to_uniform(o0 ^ o1);
}

__device__ __forceinline__ int cell_coord(float p, float lo, float invh, int G) {
  int i = (int)floorf((p - lo) * invh);
  return min(max(i, 0), G - 1);
}

// sample id -> position + weight (exact JAX RNG; partitionable split of key(42))
__device__ __forceinline__ float4 gen_sample(int id, const float* __restrict__ sv,
                                             const int* __restrict__ sfc,
                                             const float* __restrict__ fp, int NFP) {
  int face = id / NUM_SAMPLES;
  uint32_t a0, a1, b0, b1;
  threefry2x32(0u, 42u, 0u, 0u, a0, a1);  // rk1
  threefry2x32(0u, 42u, 0u, 1u, b0, b1);  // rk2
  float r1 = jax_uniform_at(a0, a1, (uint32_t)id);
  float r2 = jax_uniform_at(b0, b1, (uint32_t)id);
  float sr1 = sqrtf(r1);
  float ca = 1.0f - sr1;
  float cb = sr1 * (1.0f - r2);
  float cc = sr1 * r2;
  int va = sfc[3*face], vb = sfc[3*face+1], vc = sfc[3*face+2];
  float px = ca*sv[3*va]   + cb*sv[3*vb]   + cc*sv[3*vc];
  float py = ca*sv[3*va+1] + cb*sv[3*vb+1] + cc*sv[3*vc+1];
  float pz = ca*sv[3*va+2] + cb*sv[3*vb+2] + cc*sv[3*vc+2];
  float w = (face < NFP) ? fp[face] : 0.0f;
  return make_float4(px, py, pz, w);
}

// ---------------- prep: barycenters + vertex float4 + histograms (3 grids)
__global__ __launch_bounds__(256) void prep_kernel(
    const float* __restrict__ ov, const int* __restrict__ ofc,
    const float* __restrict__ sv, const int* __restrict__ sfc,
    const float* __restrict__ fp,
    float4* __restrict__ ob4, float4* __restrict__ sb4, float4* __restrict__ ov4,
    int* __restrict__ cnt, int NOF, int NSF, int NOV, int NFP, int nsamp) {
  int i = blockIdx.x * blockDim.x + threadIdx.x;
  int total = NOF + NSF + NOV + nsamp;
  if (i >= total) return;
  if (i < NOF) {
    int a = ofc[3*i], b = ofc[3*i+1], c = ofc[3*i+2];
    float x = (ov[3*a]   + ov[3*b]   + ov[3*c])   / 3.0f;
    float y = (ov[3*a+1] + ov[3*b+1] + ov[3*c+1]) / 3.0f;
    float z = (ov[3*a+2] + ov[3*b+2] + ov[3*c+2]) / 3.0f;
    ob4[i] = make_float4(x, y, z, x*x + y*y + z*z);
    const float invh = (float)G2 / (G2HI - G2LO);
    int cx = cell_coord(x, G2LO, invh, G2);
    int cy = cell_coord(y, G2LO, invh, G2);
    int cz = cell_coord(z, G2LO, invh, G2);
    atomicAdd(&cnt[NCELL1 + (cz*G2 + cy)*G2 + cx], 1);
  } else if (i < NOF + NSF) {
    int j = i - NOF;
    int a = sfc[3*j], b = sfc[3*j+1], c = sfc[3*j+2];
    float x = (sv[3*a]   + sv[3*b]   + sv[3*c])   / 3.0f;
    float y = (sv[3*a+1] + sv[3*b+1] + sv[3*c+1]) / 3.0f;
    float z = (sv[3*a+2] + sv[3*b+2] + sv[3*c+2]) / 3.0f;
    sb4[j] = make_float4(x, y, z, x*x + y*y + z*z);
  } else if (i < NOF + NSF + NOV) {
    int j = i - NOF - NSF;
    float x = ov[3*j], y = ov[3*j+1], z = ov[3*j+2];
    ov4[j] = make_float4(x, y, z, x*x + y*y + z*z);
    const float invh = (float)G1 / (G1HI - G1LO);
    int cx = cell_coord(x, G1LO, invh, G1);
    int cy = cell_coord(y, G1LO, invh, G1);
    int cz = cell_coord(z, G1LO, invh, G1);
    atomicAdd(&cnt[(cz*G1 + cy)*G1 + cx], 1);
  } else {
    int j = i - NOF - NSF - NOV;
    float4 s = gen_sample(j, sv, sfc, fp, NFP);
    const float invh = (float)G3 / (G3HI - G3LO);
    int cx = cell_coord(s.x, G3LO, invh, G3);
    int cy = cell_coord(s.y, G3LO, invh, G3);
    int cz = cell_coord(s.z, G3LO, invh, G3);
    atomicAdd(&cnt[NCELL1 + NCELL2 + (cz*G3 + cy)*G3 + cx], 1);
  }
}

// ---------------- fused parallel scan (publish aggregate + parallel poll)
// All SCAN_BLOCKS=248 blocks are co-resident on 256 CUs -> no deadlock.
__global__ __launch_bounds__(256) void scan_kernel(
    const int4* __restrict__ cnt4, unsigned long long* __restrict__ gsum,
    int* __restrict__ cs, int* __restrict__ cur) {
  __shared__ int lds[256];
  __shared__ int wsum[4];
  __shared__ int boffS;
  int t = threadIdx.x;
  int gid = blockIdx.x * 256 + t;
  int4 c = cnt4[gid];
  int s01 = c.x + c.y;
  int tsum = s01 + c.z + c.w;
  lds[t] = tsum;
  __syncthreads();
  for (int d = 1; d < 256; d <<= 1) {
    int u = (t >= d) ? lds[t - d] : 0;
    __syncthreads();
    lds[t] += u;
    __syncthreads();
  }
  int incl = lds[t];
  int agg  = lds[255];
  if (t == 0)
    atomicExch(&gsum[blockIdx.x], (1ULL << 63) | (unsigned long long)(unsigned)agg);
  // parallel poll of all predecessor aggregates
  int pre = 0;
  if (t < (int)blockIdx.x) {
    unsigned long long v;
    do { v = atomicAdd(&gsum[t], 0ULL); } while (!(v >> 63));
    pre = (int)(v & 0xFFFFFFFFULL);
  }
  for (int o = 32; o > 0; o >>= 1) pre += __shfl_down(pre, o);
  if ((t & 63) == 0) wsum[t >> 6] = pre;
  __syncthreads();
  if (t == 0) boffS = wsum[0] + wsum[1] + wsum[2] + wsum[3];
  __syncthreads();
  int base = boffS + incl - tsum;
  int4 o4;
  o4.x = base;
  o4.y = base + c.x;
  o4.z = base + s01;
  o4.w = base + s01 + c.z;
  ((int4*)cs)[gid] = o4;
  ((int4*)cur)[gid] = o4;
  if (blockIdx.x == gridDim.x - 1 && t == 255) cs[NTOTALL] = boffS + incl;
}

// ---------------- scatter points + samples into cell-sorted order
__global__ __launch_bounds__(256) void scatter_kernel(
    const float4* __restrict__ ov4, const float4* __restrict__ ob4,
    const float* __restrict__ sv, const int* __restrict__ sfc,
    const float* __restrict__ fp,
    int* __restrict__ cur, float4* __restrict__ sorted,
    int NOV, int NOF, int NFP, int nsamp) {
  int i = blockIdx.x * blockDim.x + threadIdx.x;
  if (i >= NOV + NOF + nsamp) return;
  float4 p; int c;
  if (i < NOV) {
    p = ov4[i];
    const float invh = (float)G1 / (G1HI - G1LO);
    int cx = cell_coord(p.x, G1LO, invh, G1);
    int cy = cell_coord(p.y, G1LO, invh, G1);
    int cz = cell_coord(p.z, G1LO, invh, G1);
    c = (cz*G1 + cy)*G1 + cx;
  } else if (i < NOV + NOF) {
    p = ob4[i - NOV];
    const float invh = (float)G2 / (G2HI - G2LO);
    int cx = cell_coord(p.x, G2LO, invh, G2);
    int cy = cell_coord(p.y, G2LO, invh, G2);
    int cz = cell_coord(p.z, G2LO, invh, G2);
    c = NCELL1 + (cz*G2 + cy)*G2 + cx;
  } else {
    int j = i - NOV - NOF;
    p = gen_sample(j, sv, sfc, fp, NFP);   // regenerate (saves a 4 MB staging array)
    const float invh = (float)G3 / (G3HI - G3LO);
    int cx = cell_coord(p.x, G3LO, invh, G3);
    int cy = cell_coord(p.y, G3LO, invh, G3);
    int cz = cell_coord(p.z, G3LO, invh, G3);
    c = NCELL1 + NCELL2 + (cz*G3 + cy)*G3 + cx;
  }
  int idx = atomicAdd(&cur[c], 1);
  sorted[idx] = p;
}

// ---------------- cooperative 16-lane exact 1-NN (group-uniform control flow)
__device__ __forceinline__ float group_min16(float v) {
  for (int o = 8; o > 0; o >>= 1) v = fminf(v, __shfl_xor(v, o, 16));
  return v;
}

__device__ float nn_group(float px, float py, float pz, float q2,
                          const int* __restrict__ cs, const float4* __restrict__ pts,
                          int G, float lo, float h, int cellofs, int lane) {
  const float invh = 1.0f / h;
  int ix = cell_coord(px, lo, invh, G);
  int iy = cell_coord(py, lo, invh, G);
  int iz = cell_coord(pz, lo, invh, G);
  float m2x = -2.0f*px, m2y = -2.0f*py, m2z = -2.0f*pz;
  float best = FLT_MAX;  // per-lane partial
  for (int r = 0; r < G; ++r) {
    float bmin = group_min16(best);
    if (r >= 1) {
      float bd = (float)(r - 1) * h;
      if (bmin + q2 <= bd * bd) break;
    }
    int z0 = max(iz - r, 0), z1 = min(iz + r, G - 1);
    int y0 = max(iy - r, 0), y1 = min(iy + r, G - 1);
    int x0 = max(ix - r, 0), x1 = min(ix + r, G - 1);
    for (int zz = z0; zz <= z1; ++zz) {
      int adz = abs(zz - iz);
      for (int yy = y0; yy <= y1; ++yy) {
        int ady = abs(yy - iy);
        int rowbase = cellofs + (zz*G + yy)*G;
        if (adz == r || ady == r) {
          int s = cs[rowbase + x0];
          int e = cs[rowbase + x1 + 1];
          for (int i = s + lane; i < e; i += GS) {
            float4 v = pts[i];
            best = fminf(best, fmaf(v.z, m2z, fmaf(v.y, m2y, fmaf(v.x, m2x, v.w))));
          }
        } else {
          if (ix - r >= 0) {
            int cc = rowbase + ix - r;
            int s = cs[cc], e = cs[cc + 1];
            for (int i = s + lane; i < e; i += GS) {
              float4 v = pts[i];
              best = fminf(best, fmaf(v.z, m2z, fmaf(v.y, m2y, fmaf(v.x, m2x, v.w))));
            }
          }
          if (r > 0 && ix + r <= G - 1) {
            int cc = rowbase + ix + r;
            int s = cs[cc], e = cs[cc + 1];
            for (int i = s + lane; i < e; i += GS) {
              float4 v = pts[i];
              best = fminf(best, fmaf(v.z, m2z, fmaf(v.y, m2y, fmaf(v.x, m2x, v.w))));
            }
          }
        }
      }
    }
  }
  return group_min16(best);
}

// ---------------- fused queries (grid-stride over fwd+rev groups) + last-block final
__global__ __launch_bounds__(256) void query_kernel(
    const float* __restrict__ fp, const float4* __restrict__ sb4,
    const int* __restrict__ cs, const float4* __restrict__ sorted,
    float* __restrict__ acc, float* __restrict__ out,
    int NSF, int NFP, int nsamp, int sampBase) {
  const float h1 = (G1HI - G1LO) / (float)G1;
  const float h2 = (G2HI - G2LO) / (float)G2;
  int lane = threadIdx.x & (GS - 1);
  int grpInBlk = threadIdx.x / GS;       // 0..15
  const int grpsPerBlk = 256 / GS;       // 16
  int totalGroups = NSF + nsamp;
  float facc = 0.0f, racc = 0.0f, rmaxv = 0.0f;
  for (int g = blockIdx.x * grpsPerBlk + grpInBlk; g < totalGroups;
       g += gridDim.x * grpsPerBlk) {
    if (g < NSF) {
      float4 s = sb4[g];
      float best = nn_group(s.x, s.y, s.z, s.w, cs, sorted, G2, G2LO, h2, NCELL1, lane);
      if (lane == 0) {
        float mind = sqrtf(fmaxf(best + s.w, 0.0f));
        float p = (g < NFP) ? fp[g] : 0.0f;
        facc += p * mind;
      }
    } else {
      int sid = g - NSF;
      float4 s = sorted[sampBase + sid];
      float q2 = s.x*s.x + s.y*s.y + s.z*s.z;
      float best = nn_group(s.x, s.y, s.z, q2, cs, sorted, G1, G1LO, h1, 0, lane);
      if (lane == 0) {
        float d = sqrtf(fmaxf(best + q2, 0.0f));
        racc += s.w * d;
        rmaxv = fmaxf(rmaxv, d);
      }
    }
  }
  // block reduce (non-leader lanes hold 0)
  __shared__ float sF[4], sR[4], sM[4];
  __shared__ int isLast;
  __shared__ float stash[4];
  for (int o = 32; o > 0; o >>= 1) {
    facc += __shfl_down(facc, o);
    racc += __shfl_down(racc, o);
    rmaxv = fmaxf(rmaxv, __shfl_down(rmaxv, o));
  }
  int wid = threadIdx.x >> 6;
  if ((threadIdx.x & 63) == 0) { sF[wid] = facc; sR[wid] = racc; sM[wid] = rmaxv; }
  __syncthreads();
  if (threadIdx.x == 0) {
    float tf = sF[0] + sF[1] + sF[2] + sF[3];
    float tr = sR[0] + sR[1] + sR[2] + sR[3];
    float tm = fmaxf(fmaxf(sM[0], sM[1]), fmaxf(sM[2], sM[3]));
    int slot = (blockIdx.x & 63) * 16;
    atomicAdd(&acc[slot], tf);
    atomicAdd(&acc[1024 + slot], tr);
    atomicMax((int*)acc + 2048 + slot, __float_as_int(tm));
    __threadfence();
    int old = atomicAdd((int*)acc + 3072, 1);
    isLast = (old == (int)gridDim.x - 1) ? 1 : 0;
  }
  __syncthreads();
  if (!isLast) return;

  // ---- final: this is the last block; read slots coherently via atomic RMWs ----
  __shared__ float red[256];
  int t = threadIdx.x;
  float fsum = 0.0f, rsum = 0.0f, rmx = 0.0f;
  if (t < 64)        fsum = atomicAdd(&acc[t * 16], 0.0f);
  else if (t < 128)  rsum = atomicAdd(&acc[1024 + (t - 64) * 16], 0.0f);
  else if (t < 192)  rmx  = __int_as_float(atomicMax((int*)acc + 2048 + (t - 128) * 16, 0));
  float sfp = 0.0f;
  for (int i = t; i < NSF; i += 256) sfp += (i < NFP) ? fp[i] : 0.0f;

  // reduce fsum (sum)
  red[t] = fsum; __syncthreads();
  for (int o = 128; o > 0; o >>= 1) { if (t < o) red[t] += red[t + o]; __syncthreads(); }
  if (t == 0) stash[0] = red[0];
  __syncthreads();
  // reduce rsum (sum)
  red[t] = rsum; __syncthreads();
  for (int o = 128; o > 0; o >>= 1) { if (t < o) red[t] += red[t + o]; __syncthreads(); }
  if (t == 0) stash[1] = red[0];
  __syncthreads();
  // reduce rmx (max)
  red[t] = rmx; __syncthreads();
  for (int o = 128; o > 0; o >>= 1) { if (t < o) red[t] = fmaxf(red[t], red[t + o]); __syncthreads(); }
  if (t == 0) stash[2] = red[0];
  __syncthreads();
  // reduce sfp (sum)
  red[t] = sfp; __syncthreads();
  for (int o = 128; o > 0; o >>= 1) { if (t < o) red[t] += red[t + o]; __syncthreads(); }
  if (t == 0) {
    float fwd = stash[0] + PENALTY * ((float)NSF - red[0]);
    float rev = stash[1] * (REV_SCALE / (stash[2] + EPSF));
    out[0] = fwd + rev;
  }
}

extern "C" void kernel_launch(void* const* d_in, const int* in_sizes, int n_in,
                              void* d_out, int out_size, void* d_ws, size_t ws_size,
                              hipStream_t stream) {
  const float* ov  = (const float*)d_in[0];
  const int*   ofc = (const int*)  d_in[1];
  const float* sv  = (const float*)d_in[2];
  const int*   sfc = (const int*)  d_in[3];
  const float* fp  = (const float*)d_in[4];
  float* out = (float*)d_out;

  int NOV = in_sizes[0] / 3;
  int NOF = in_sizes[1] / 3;
  int NSF = in_sizes[3] / 3;
  int NFP = in_sizes[4];
  int nsamp = NSF * NUM_SAMPLES;

  // ws layout: [acc 16KB][gsum 2KB][cnt][cs][cur][float4 arrays]
  char* w = (char*)d_ws;
  float* acc = (float*)w;                       w += ACC_FLOATS * 4;       // 16 KB
  unsigned long long* gsum = (unsigned long long*)w; w += 2048;            // 2 KB
  int*   cnt = (int*)w;                         w += (size_t)NTOTALL * 4;
  size_t zeroBytes = (size_t)(w - (char*)d_ws); // acc + gsum + cnt, contiguous
  int*   cs  = (int*)w;                         w += (size_t)(NTOTALL + 16) * 4;
  int*   cur = (int*)w;                         w += (size_t)NTOTALL * 4;
  float4* ob4    = (float4*)w;  w += (size_t)NOF * 16;
  float4* sb4    = (float4*)w;  w += (size_t)NSF * 16;
  float4* ov4    = (float4*)w;  w += (size_t)NOV * 16;
  float4* sorted = (float4*)w;  w += (size_t)(NOV + NOF + nsamp) * 16;

  hipMemsetAsync(d_ws, 0, zeroBytes, stream);

  int total = NOF + NSF + NOV + nsamp;
  hipLaunchKernelGGL(prep_kernel, dim3((total + 255) / 256), dim3(256), 0, stream,
                     ov, ofc, sv, sfc, fp, ob4, sb4, ov4, cnt, NOF, NSF, NOV, NFP, nsamp);

  hipLaunchKernelGGL(scan_kernel, dim3(SCAN_BLOCKS), dim3(256), 0, stream,
                     (const int4*)cnt, gsum, cs, cur);

  hipLaunchKernelGGL(scatter_kernel, dim3((NOV + NOF + nsamp + 255) / 256), dim3(256), 0, stream,
                     ov4, ob4, sv, sfc, fp, cur, sorted, NOV, NOF, NFP, nsamp);

  hipLaunchKernelGGL(query_kernel, dim3(QBLOCKS), dim3(256), 0, stream,
                     fp, sb4, cs, sorted, acc, out, NSF, NFP, nsamp, NOV + NOF);
}